// Round 3
// baseline (689.267 us; speedup 1.0000x reference)
//
#include <hip/hip_runtime.h>
#include <math.h>

// B=8, T=2048 -> M = 16384 rows; V=4096; C=128; 2NB=128; NOPS=8
#define M_TOT 16384
#define V_DIM 4096
#define C_DIM 128

typedef __bf16 bf16;
typedef __bf16 bf16x8 __attribute__((ext_vector_type(8)));
typedef float f32x4 __attribute__((ext_vector_type(4)));

__device__ inline f32x4 zero4() { f32x4 z; z[0]=0.f; z[1]=0.f; z[2]=0.f; z[3]=0.f; return z; }

__device__ inline bf16 f2bf(float f) {
  union { float f; unsigned u; } a; a.f = f;
  unsigned r = (a.u + 0x7FFFu + ((a.u >> 16) & 1u)) >> 16;
  union { unsigned short s; bf16 b; } o; o.s = (unsigned short)r;
  return o.b;
}

__device__ inline bf16x8 cvt8(float4 a, float4 b) {
  bf16x8 r;
  r[0]=f2bf(a.x); r[1]=f2bf(a.y); r[2]=f2bf(a.z); r[3]=f2bf(a.w);
  r[4]=f2bf(b.x); r[5]=f2bf(b.y); r[6]=f2bf(b.z); r[7]=f2bf(b.w);
  return r;
}

// ---------------------------------------------------------------------------
// k_prep: fused {logits, w2, ops-transpose} (unchanged, proven)
// blocks 0..31   : LT[c][v] = rc[c,:] . basis[v,:]      (fp32, MFMA)
// blocks 32..95  : W2[v][c] = basis[v,:] . wc[c,:]      (bf16, MFMA)
// blocks 96..607 : WTO[i][n][k] = op_weights[i][k][n]   (bf16 transpose)
// ---------------------------------------------------------------------------
union PrepU {
  struct { bf16 A[128][136]; bf16 B[128][136]; } lg;
  struct { bf16 A[64][136];  bf16 B[128][136]; } w2;
};

__global__ __launch_bounds__(256) void k_prep(const float* __restrict__ basis,
                                              const float* __restrict__ rc,
                                              const float* __restrict__ wc,
                                              const float* __restrict__ opw,
                                              float* __restrict__ LT,
                                              bf16* __restrict__ W2,
                                              bf16* __restrict__ WTO) {
  __shared__ __align__(16) PrepU pu;
  const int t = threadIdx.x;
  const int bid = blockIdx.x;
  const int lane = t & 63, wave = t >> 6, fm = lane & 15, quad = lane >> 4;

  if (bid < 32) {  // ----- logits -----
    const int v0 = bid * 128;
    {
      const int row = t >> 1, c0 = (t & 1) * 64;
      const float4* p = (const float4*)(rc + row * 128 + c0);
      bf16x8* d = (bf16x8*)&pu.lg.A[row][c0];
#pragma unroll
      for (int j = 0; j < 8; j++) { float4 a = p[2*j], b = p[2*j+1]; d[j] = cvt8(a, b); }
    }
    {
      const int row = t >> 1, c0 = (t & 1) * 64;
      const float4* p = (const float4*)(basis + (size_t)(v0 + row) * 128 + c0);
      bf16x8* d = (bf16x8*)&pu.lg.B[row][c0];
#pragma unroll
      for (int j = 0; j < 8; j++) { float4 a = p[2*j], b = p[2*j+1]; d[j] = cvt8(a, b); }
    }
    __syncthreads();

    f32x4 acc[2][8];
#pragma unroll
    for (int m = 0; m < 2; m++)
#pragma unroll
      for (int n = 0; n < 8; n++) acc[m][n] = zero4();

#pragma unroll
    for (int kk = 0; kk < 4; kk++) {
      bf16x8 af[2];
#pragma unroll
      for (int m = 0; m < 2; m++)
        af[m] = *(const bf16x8*)&pu.lg.A[wave * 32 + m * 16 + fm][kk * 32 + quad * 8];
#pragma unroll
      for (int nt = 0; nt < 8; nt++) {
        bf16x8 bfr = *(const bf16x8*)&pu.lg.B[nt * 16 + fm][kk * 32 + quad * 8];
#pragma unroll
        for (int m = 0; m < 2; m++)
          acc[m][nt] = __builtin_amdgcn_mfma_f32_16x16x32_bf16(af[m], bfr, acc[m][nt], 0, 0, 0);
      }
    }
#pragma unroll
    for (int m = 0; m < 2; m++)
#pragma unroll
      for (int nt = 0; nt < 8; nt++)
#pragma unroll
        for (int r = 0; r < 4; r++) {
          int c = wave * 32 + m * 16 + quad * 4 + r;
          LT[(size_t)c * V_DIM + v0 + nt * 16 + fm] = acc[m][nt][r];
        }
  } else if (bid < 96) {  // ----- w2 -----
    const int v0 = (bid - 32) * 64;
    {
      const int row = t >> 2, c0 = (t & 3) * 32;
      const float4* p = (const float4*)(basis + (size_t)(v0 + row) * 128 + c0);
      bf16x8* d = (bf16x8*)&pu.w2.A[row][c0];
#pragma unroll
      for (int j = 0; j < 4; j++) { float4 a = p[2*j], b = p[2*j+1]; d[j] = cvt8(a, b); }
    }
    {
      const int row = t >> 1, c0 = (t & 1) * 64;
      const float4* p = (const float4*)(wc + row * 128 + c0);
      bf16x8* d = (bf16x8*)&pu.w2.B[row][c0];
#pragma unroll
      for (int j = 0; j < 8; j++) { float4 a = p[2*j], b = p[2*j+1]; d[j] = cvt8(a, b); }
    }
    __syncthreads();

    f32x4 acc[8];
#pragma unroll
    for (int n = 0; n < 8; n++) acc[n] = zero4();
#pragma unroll
    for (int kk = 0; kk < 4; kk++) {
      bf16x8 af = *(const bf16x8*)&pu.w2.A[wave * 16 + fm][kk * 32 + quad * 8];
#pragma unroll
      for (int nt = 0; nt < 8; nt++) {
        bf16x8 bfr = *(const bf16x8*)&pu.w2.B[nt * 16 + fm][kk * 32 + quad * 8];
        acc[nt] = __builtin_amdgcn_mfma_f32_16x16x32_bf16(af, bfr, acc[nt], 0, 0, 0);
      }
    }
#pragma unroll
    for (int nt = 0; nt < 8; nt++)
#pragma unroll
      for (int r = 0; r < 4; r++) {
        int v = v0 + wave * 16 + quad * 4 + r;
        W2[v * 128 + nt * 16 + fm] = f2bf(acc[nt][r]);
      }
  } else {  // ----- ops transpose -----
    int idx = (bid - 96) * 256 + t;  // 131072 total
    int i = idx >> 14, rem = idx & 16383, n = rem >> 7, k = rem & 127;
    WTO[idx] = f2bf(opw[(i << 14) + k * 128 + n]);
  }
}

// ---------------------------------------------------------------------------
// k_softmax: RT[c][v] = softmax_v(LT[c][v])   (bf16), block per c (unchanged)
// ---------------------------------------------------------------------------
__global__ __launch_bounds__(256) void k_softmax(const float* __restrict__ LT,
                                                 bf16* __restrict__ RT) {
  const int c = blockIdx.x, t = threadIdx.x;
  __shared__ float red[256];
  const float* row = LT + (size_t)c * V_DIM;
  float e[16];
  float lmax = -3.0e38f;
#pragma unroll
  for (int j = 0; j < 16; j++) { e[j] = row[t + 256 * j]; lmax = fmaxf(lmax, e[j]); }
  red[t] = lmax;
  __syncthreads();
  for (int off = 128; off > 0; off >>= 1) {
    if (t < off) red[t] = fmaxf(red[t], red[t + off]);
    __syncthreads();
  }
  const float gmax = red[0];
  __syncthreads();
  float lsum = 0.f;
#pragma unroll
  for (int j = 0; j < 16; j++) { e[j] = __expf(e[j] - gmax); lsum += e[j]; }
  red[t] = lsum;
  __syncthreads();
  for (int off = 128; off > 0; off >>= 1) {
    if (t < off) red[t] += red[t + off];
    __syncthreads();
  }
  const float inv = 1.f / red[0];
#pragma unroll
  for (int j = 0; j < 16; j++)
    RT[(size_t)c * V_DIM + t + 256 * j] = f2bf(e[j] * inv);
}

// ---------------------------------------------------------------------------
// nonlinearities for the op bank
// ---------------------------------------------------------------------------
__device__ inline float apply_nonlin(int i, float v) {
  switch (i) {
    case 0: return v;
    case 1: return fmaxf(v, 0.f);
    case 2: return 0.5f * v * (1.f + erff(v * 0.70710678118654752f));
    case 3: return v * v;
    case 4: return -v;
    case 5: return fabsf(v);
    case 6: return tanhf(v);
    default: return 1.f / (1.f + __expf(-v));
  }
}

// ---------------------------------------------------------------------------
// k_main v2: fused gemm1+opbank+gemm2, LATENCY-ORIENTED rewrite.
//   512 threads (8 waves = 2/SIMD), 64 rows/block, grid 256.
//   All B operands (RT/WTO/W2: 2.25 MB total, L2-resident per XCD) are loaded
//   per-lane DIRECTLY global->register as contiguous 16B dwordx4 fragments:
//   no LDS staging, no bank conflicts, no per-step barriers (4 total).
//   phase 1: K split across wave-halves (wh), fp32 acc; cross-wave reduce
//            via LDS R (fp32, MORE accurate than old bf16 split-K partials).
//   phase 2: op bank, N split across wave-halves (4 nt each).
//   phase 3: 32 n-tiles split 16/16 across wave-halves, direct stores.
//   VMEM issue order arranged so every vmcnt wait only forces older loads:
//   per step: [wait aX] cvt -> issue aX(next) -> [wait BbX] MFMA -> issue
//   BbX(next), with E/O banks (all static register indexing).
// ---------------------------------------------------------------------------
__global__ __launch_bounds__(512, 2) void k_main(const float* __restrict__ x,
                                                 const bf16* __restrict__ RT,
                                                 const bf16* __restrict__ WTO,
                                                 const bf16* __restrict__ W2,
                                                 const float* __restrict__ op_logits,
                                                 const float* __restrict__ op_biases,
                                                 const float* __restrict__ p_scale,
                                                 float* __restrict__ out) {
  __shared__ float R[64][132];          // fp32 k-split partials (33.8 KB)
  __shared__ __align__(16) bf16 S[64][136];  // vals / res transposer (17.4 KB)
  const int t = threadIdx.x;
  const int m0 = blockIdx.x * 64;
  const int lane = t & 63, wave = t >> 6;
  const int fm = lane & 15, quad = lane >> 4;
  const int wg = wave & 3;   // row group (16 rows)
  const int wh = wave >> 2;  // half: k-half (p1) / n-half (p2, p3)

  // ===================== phase 1: vals = x @ RT^T (K split) ===================
  const float* xp = x + (size_t)(m0 + wg * 16 + fm) * V_DIM + wh * 2048 + quad * 8;
  const bf16*  rp = RT + (size_t)fm * V_DIM + wh * 2048 + quad * 8;

  f32x4 acc[8];
#pragma unroll
  for (int i = 0; i < 8; i++) acc[i] = zero4();

#define P1_LA(A0, A1, A2, A3, koff)                                            \
  {                                                                            \
    A0 = *(const float4*)(xp + (koff));                                        \
    A1 = *(const float4*)(xp + (koff) + 4);                                    \
    A2 = *(const float4*)(xp + (koff) + 32);                                   \
    A3 = *(const float4*)(xp + (koff) + 36);                                   \
  }
#define P1_LB(BB, koff)                                                        \
  {                                                                            \
    _Pragma("unroll")                                                          \
    for (int nt = 0; nt < 8; nt++) {                                           \
      BB[2 * nt]     = *(const bf16x8*)(rp + (size_t)nt * 16 * V_DIM + (koff));        \
      BB[2 * nt + 1] = *(const bf16x8*)(rp + (size_t)nt * 16 * V_DIM + (koff) + 32);   \
    }                                                                          \
  }
#define P1_MM(af0, af1, BB)                                                    \
  {                                                                            \
    _Pragma("unroll")                                                          \
    for (int nt = 0; nt < 8; nt++) {                                           \
      acc[nt] = __builtin_amdgcn_mfma_f32_16x16x32_bf16(af0, BB[2 * nt], acc[nt], 0, 0, 0);     \
      acc[nt] = __builtin_amdgcn_mfma_f32_16x16x32_bf16(af1, BB[2 * nt + 1], acc[nt], 0, 0, 0); \
    }                                                                          \
  }

  {
    float4 aE0, aE1, aE2, aE3, aO0, aO1, aO2, aO3;
    bf16x8 BbE[16], BbO[16];
    P1_LA(aE0, aE1, aE2, aE3, 0);
    P1_LB(BbE, 0);
    P1_LA(aO0, aO1, aO2, aO3, 64);
    P1_LB(BbO, 64);
    for (int s = 0; s < 16; s++) {
      const int k0 = s * 128;
      {  // even half-step
        bf16x8 af0 = cvt8(aE0, aE1), af1 = cvt8(aE2, aE3);  // waits aE only
        if (s < 15) P1_LA(aE0, aE1, aE2, aE3, k0 + 128);
        P1_MM(af0, af1, BbE);                               // waits BbE only
        if (s < 15) P1_LB(BbE, k0 + 128);
      }
      {  // odd half-step
        bf16x8 af0 = cvt8(aO0, aO1), af1 = cvt8(aO2, aO3);
        if (s < 15) P1_LA(aO0, aO1, aO2, aO3, k0 + 192);
        P1_MM(af0, af1, BbO);
        if (s < 15) P1_LB(BbO, k0 + 192);
      }
    }
  }
#undef P1_LA
#undef P1_LB
#undef P1_MM

  // cross-wave K reduction (fp32) + transpose into S (bf16, A-operand layout)
  if (wh == 1) {
#pragma unroll
    for (int nt = 0; nt < 8; nt++)
#pragma unroll
      for (int r = 0; r < 4; r++)
        R[wg * 16 + quad * 4 + r][nt * 16 + fm] = acc[nt][r];
  }

  // softmax over op_logits (all threads, tiny; overlaps barrier)
  float w[8];
  {
    float lm = -3.0e38f;
#pragma unroll
    for (int i = 0; i < 8; i++) { w[i] = op_logits[i]; lm = fmaxf(lm, w[i]); }
    float ssum = 0.f;
#pragma unroll
    for (int i = 0; i < 8; i++) { w[i] = __expf(w[i] - lm); ssum += w[i]; }
    float inv = 1.f / ssum;
#pragma unroll
    for (int i = 0; i < 8; i++) w[i] *= inv;
  }

  __syncthreads();  // R visible
  if (wh == 0) {
#pragma unroll
    for (int nt = 0; nt < 8; nt++)
#pragma unroll
      for (int r = 0; r < 4; r++) {
        float sum = acc[nt][r] + R[wg * 16 + quad * 4 + r][nt * 16 + fm];
        S[wg * 16 + quad * 4 + r][nt * 16 + fm] = f2bf(sum);
      }
  }
  __syncthreads();  // S (vals) visible

  // ===================== phase 2: op bank (N split) ===========================
  bf16x8 af[4];
#pragma unroll
  for (int kk = 0; kk < 4; kk++)
    af[kk] = *(const bf16x8*)&S[wg * 16 + fm][kk * 32 + quad * 8];

  f32x4 res[4];
#pragma unroll
  for (int j = 0; j < 4; j++) res[j] = zero4();

#pragma unroll
  for (int i = 0; i < 8; i++) {
#pragma unroll
    for (int j = 0; j < 4; j++) {
      const int n = (wh * 4 + j) * 16 + fm;
      const bf16* wp = WTO + i * 16384 + (size_t)n * 128 + quad * 8;
      f32x4 h = zero4();
#pragma unroll
      for (int kk = 0; kk < 4; kk++) {
        bf16x8 b = *(const bf16x8*)(wp + kk * 32);
        h = __builtin_amdgcn_mfma_f32_16x16x32_bf16(af[kk], b, h, 0, 0, 0);
      }
      const float bias = op_biases[i * 128 + n];
#pragma unroll
      for (int r = 0; r < 4; r++)
        res[j][r] += w[i] * apply_nonlin(i, h[r] + bias);
    }
  }

  __syncthreads();  // everyone done reading S(vals)
#pragma unroll
  for (int j = 0; j < 4; j++)
#pragma unroll
    for (int r = 0; r < 4; r++)
      S[wg * 16 + quad * 4 + r][wh * 64 + j * 16 + fm] = f2bf(res[j][r]);
  __syncthreads();  // S (res) visible

  // ===================== phase 3: out = scale * res @ W2^T (tiles split) ======
  bf16x8 af2[4];
#pragma unroll
  for (int kk = 0; kk < 4; kk++)
    af2[kk] = *(const bf16x8*)&S[wg * 16 + fm][kk * 32 + quad * 8];

  const float scale = *p_scale;
  const size_t orow = (size_t)(m0 + wg * 16 + quad * 4);

  for (int tt = 0; tt < 16; tt++) {
    const int ti = wh * 16 + tt;
#pragma unroll
    for (int nt = 0; nt < 8; nt++) {
      const bf16* wp = W2 + ((size_t)ti * 128 + nt * 16 + fm) * 128 + quad * 8;
      f32x4 a2 = zero4();
#pragma unroll
      for (int kk = 0; kk < 4; kk++) {
        bf16x8 b = *(const bf16x8*)(wp + kk * 32);
        a2 = __builtin_amdgcn_mfma_f32_16x16x32_bf16(af2[kk], b, a2, 0, 0, 0);
      }
#pragma unroll
      for (int r = 0; r < 4; r++)
        out[(orow + r) * V_DIM + ti * 128 + nt * 16 + fm] = a2[r] * scale;
    }
  }
}

// ---------------------------------------------------------------------------
// launch
// ---------------------------------------------------------------------------
extern "C" void kernel_launch(void* const* d_in, const int* in_sizes, int n_in,
                              void* d_out, int out_size, void* d_ws, size_t ws_size,
                              hipStream_t stream) {
  const float* x      = (const float*)d_in[0];
  const float* basis  = (const float*)d_in[1];
  const float* rc     = (const float*)d_in[2];
  const float* wc     = (const float*)d_in[3];
  const float* oplog  = (const float*)d_in[4];
  const float* opw    = (const float*)d_in[5];
  const float* opb    = (const float*)d_in[6];
  const float* oscale = (const float*)d_in[7];
  float* out = (float*)d_out;
  char* ws = (char*)d_ws;

  // workspace layout (~4.5 MB)
  float* LT  = (float*)(ws);                    // 2 MB   (C,V) fp32 logits
  bf16* RT   = (bf16*)(ws + 2097152);           // 1 MB   (C,V)
  bf16* W2   = (bf16*)(ws + 3145728);           // 1 MB   (V,C)
  bf16* WTO  = (bf16*)(ws + 4194304);           // 256 KB (8,n,k)

  k_prep   <<<608, 256, 0, stream>>>(basis, rc, wc, opw, LT, W2, WTO);
  k_softmax<<<C_DIM, 256, 0, stream>>>(LT, RT);
  k_main   <<<M_TOT / 64, 512, 0, stream>>>(x, RT, WTO, W2, oplog, opb, oscale, out);
}